// Round 5
// baseline (27.689 us; speedup 1.0000x reference)
//
#include <hip/hip_runtime.h>

// x: (B=2048, S=1024, D=12) f32. K = select_num = VOTE_PERHEAD = 24. S = 32*32.
// One 64-lane wave per batch row; zero __syncthreads.
constexpr int S_ = 1024;
constexpr int D_ = 12;
constexpr int K_ = 24;
constexpr int NL = 5;

__device__ __forceinline__ void stamp3x3(int p, unsigned int* convp) {
    int r = p >> 5, c0 = p & 31;
    #pragma unroll
    for (int dr = -1; dr <= 1; ++dr) {
        int rr = r + dr;
        if (rr < 0 || rr >= 32) continue;
        #pragma unroll
        for (int dc = -1; dc <= 1; ++dc) {
            int cc = c0 + dc;
            if (cc < 0 || cc >= 32) continue;
            unsigned int w = ((dr == 0) ? 2u : 1u) * ((dc == 0) ? 2u : 1u);
            int q = rr * 32 + cc;
            atomicAdd(&convp[q >> 2], w << ((q & 3) * 8));  // packed u8, max 16: no carry
        }
    }
}

__global__ __launch_bounds__(64) void mhv_kernel(const float* __restrict__ x,
                                                 float* __restrict__ out_idx,  // B*K
                                                 float* __restrict__ out_cnt)  // B*S
{
    const int b    = blockIdx.x;
    const int lane = threadIdx.x;          // 0..63

    __shared__ unsigned int       convp[S_ / 4];  // packed 4x u8 conv counts (1 KB)
    __shared__ unsigned long long slab[64];       // compacted score keys
    __shared__ int                ck[96];         // count>=4 cells (24..96 by mass)

    // init conv accumulator + slab padding (wave-synchronous, in-order DS)
    #pragma unroll
    for (int j = 0; j < 4; ++j) convp[j * 64 + lane] = 0u;
    slab[lane] = 0ull;

    // ---- load 16 scores/lane, monotone bit transform ----
    const float* xb = x + (size_t)b * (S_ * D_);
    unsigned int su[16];
    #pragma unroll
    for (int i = 0; i < 16; ++i) {
        int s = i * 64 + lane;
        su[i] = 0u;                         // s==1023: no score (min)
        if (s < S_ - 1) {
            unsigned int bits = __float_as_uint(xb[(s + 1) * D_]);
            su[i] = (bits & 0x80000000u) ? ~bits : (bits | 0x80000000u);
        }
    }

    // ---- threshold ladder {2.6,2.2,1.9,1.6,1.3}sigma (monotone-transformed) ----
    const unsigned int LAD[NL] = {0xC0266666u, 0xC00CCCCDu, 0xBFF33333u,
                                  0xBFCCCCCDu, 0xBFA66666u};
    int lcnt[NL];
    #pragma unroll
    for (int j = 0; j < NL; ++j) {
        int c = 0;
        #pragma unroll
        for (int i = 0; i < 16; ++i) c += __popcll(__ballot(su[i] >= LAD[j]));
        lcnt[j] = c;
    }
    int csel = -1; unsigned int Usel = 0u;
    #pragma unroll
    for (int j = 0; j < NL; ++j)
        if (csel < 0 && lcnt[j] >= K_) { csel = lcnt[j]; Usel = LAD[j]; }

    if (csel >= K_ && csel <= 64) {
        // ---- compact candidate keys to slab (one per lane afterwards) ----
        int base = 0;
        #pragma unroll
        for (int i = 0; i < 16; ++i) {
            bool sel = (su[i] >= Usel);
            unsigned long long m = __ballot(sel);
            if (sel) {
                int s = i * 64 + lane;
                slab[base + __popcll(m & ((1ull << lane) - 1ull))] =
                    ((unsigned long long)su[i] << 10) | (unsigned)(S_ - 1 - s);
            }
            base += __popcll(m);
        }
        // ---- rank via shfl broadcast (keys unique; pad keys are 0) ----
        unsigned long long kk = slab[lane];
        int rk = 0;
        int cpad = (csel + 3) & ~3;
        for (int j = 0; j < cpad; j += 4) {
            #pragma unroll
            for (int u = 0; u < 4; ++u) {
                unsigned long long kj = __shfl(kk, j + u);
                rk += (kj > kk);
            }
        }
        if (lane < csel && rk < K_)
            stamp3x3(S_ - 1 - (int)(kk & 1023ull), convp);
    } else {
        // ---- rare exact fallback: 42-bit ballot threshold search ----
        unsigned long long k64[16];
        #pragma unroll
        for (int i = 0; i < 16; ++i)
            k64[i] = ((unsigned long long)su[i] << 10) |
                     (unsigned)(S_ - 1 - (i * 64 + lane));
        unsigned long long t = 0ull;
        for (int bit = 41; bit >= 0; --bit) {
            unsigned long long tr = t | (1ull << bit);
            int c = 0;
            #pragma unroll
            for (int i = 0; i < 16; ++i) c += __popcll(__ballot(k64[i] >= tr));
            if (c >= K_) t = tr;
        }
        // exactly K_ keys >= t (keys unique)
        #pragma unroll
        for (int i = 0; i < 16; ++i)
            if (k64[i] >= t)
                stamp3x3(S_ - 1 - (int)(k64[i] & 1023ull), convp);
    }

    // ---- unpack conv counts, write output 1, compact cells with count>=4 ----
    // Every vote center has count>=4 => 24 <= c2; mass 24*16=384 => c2 <= 96.
    int c2base = 0;
    #pragma unroll
    for (int j = 0; j < 4; ++j) {
        unsigned int pd = convp[j * 64 + lane];
        float4 o;
        o.x = (float)(pd & 255u);
        o.y = (float)((pd >> 8) & 255u);
        o.z = (float)((pd >> 16) & 255u);
        o.w = (float)(pd >> 24);
        *(float4*)(out_cnt + (size_t)b * S_ + (j * 64 + lane) * 4) = o;
        #pragma unroll
        for (int q = 0; q < 4; ++q) {
            unsigned int cv = (pd >> (q * 8)) & 255u;
            bool sel = (cv >= 4u);
            unsigned long long m = __ballot(sel);
            if (sel) {
                int p = (j * 64 + lane) * 4 + q;
                ck[c2base + __popcll(m & ((1ull << lane) - 1ull))] =
                    (int)(cv << 10) | (S_ - 1 - p);   // count desc, index asc
            }
            c2base += __popcll(m);
        }
    }

    // ---- rank2: 2 keys/lane, shfl broadcast over c2 entries ----
    int c2 = c2base;                       // 24 <= c2 <= 96 (uniform)
    int k0 = (lane < c2)      ? ck[lane]      : -1;
    int k1 = (64 + lane < c2) ? ck[64 + lane] : -1;
    int r0 = 0, r1 = 0;
    int c2pad = (c2 + 3) & ~3;
    for (int j = 0; j < c2pad; j += 4) {
        #pragma unroll
        for (int u = 0; u < 4; ++u) {
            int jj = j + u;
            int kj = (jj < 64) ? __shfl(k0, jj) : __shfl(k1, jj - 64);
            r0 += (kj > k0);
            r1 += (kj > k1);
        }
    }
    if (lane < c2 && r0 < K_)
        out_idx[(size_t)b * K_ + r0] = (float)(S_ - (k0 & 1023));  // p + 1
    if (64 + lane < c2 && r1 < K_)
        out_idx[(size_t)b * K_ + r1] = (float)(S_ - (k1 & 1023));
}

extern "C" void kernel_launch(void* const* d_in, const int* in_sizes, int n_in,
                              void* d_out, int out_size, void* d_ws, size_t ws_size,
                              hipStream_t stream) {
    const float* x = (const float*)d_in[0];
    const int B = in_sizes[0] / (S_ * D_);

    float* out     = (float*)d_out;
    float* out_idx = out;                    // B*K_ (patch_idx, 1-based, as f32)
    float* out_cnt = out + (size_t)B * K_;   // B*S_ (count)

    mhv_kernel<<<dim3(B), dim3(64), 0, stream>>>(x, out_idx, out_cnt);
}